// Round 11
// baseline (306.449 us; speedup 1.0000x reference)
//
#include <hip/hip_runtime.h>
#include <hip/hip_bf16.h>
#include <hip/hip_cooperative_groups.h>

namespace cg = cooperative_groups;

#define SELU_L 1.0507009873554805f
#define SELU_A 1.6732632423543772f

typedef float  floatx4 __attribute__((ext_vector_type(4)));
typedef short  bf16x8  __attribute__((ext_vector_type(8)));

__device__ __forceinline__ float selu(float x) {
    return x > 0.f ? SELU_L * x : SELU_L * SELU_A * (expf(x) - 1.f);
}
__device__ __forceinline__ float fast_rcp(float x) {
    return __builtin_amdgcn_rcpf(x);
}
__device__ __forceinline__ unsigned short bf16_rne(float f) {
    unsigned int u = __float_as_uint(f);
    u += 0x7fffu + ((u >> 16) & 1u);
    return (unsigned short)(u >> 16);
}
__device__ __forceinline__ void cvt8(const float* __restrict__ p,
                                     bf16x8& h8, bf16x8& l8) {
    float4 v0 = *reinterpret_cast<const float4*>(p);
    float4 v1 = *reinterpret_cast<const float4*>(p + 4);
    float f[8] = {v0.x, v0.y, v0.z, v0.w, v1.x, v1.y, v1.z, v1.w};
#pragma unroll
    for (int j = 0; j < 8; ++j) {
        const unsigned short h = bf16_rne(f[j]);
        const float hf = __uint_as_float((unsigned)h << 16);
        const unsigned short l = bf16_rne(f[j] - hf);
        h8[j] = (short)h;
        l8[j] = (short)l;
    }
}

// ============================ FUSED COOPERATIVE KERNEL ======================
__global__ __launch_bounds__(256) void fused_all(
    const float* __restrict__ x, const float* __restrict__ w,
    const float* __restrict__ fcb, const float* __restrict__ gamma,
    const float* __restrict__ beta, const float* __restrict__ fc2w,
    const float* __restrict__ fc2b, float* __restrict__ o1,
    double* __restrict__ accs, float4* __restrict__ packed,
    ushort* __restrict__ whi, ushort* __restrict__ wlo,
    float* __restrict__ o_out, float* __restrict__ qij)
{
    cg::grid_group grid = cg::this_grid();
    const int t    = threadIdx.x;
    const int bid  = blockIdx.x;
    const int nb   = gridDim.x;
    const int lane = t & 63;
    const int wv   = t >> 6;
    const int gwid = bid * 4 + wv;
    const int totW = nb * 4;

    double* sums  = accs;
    double* sumsq = accs + 128;
    double* denom = accs + 256;

    __shared__ float4 rowsh[64];
    __shared__ double wsum[4];

    // ---- Phase W: convert fc_w to hi/lo planes (K padded to 800), zero accs
    if (bid == 0 && t < 64) {
        for (int i = t; i < 257; i += 64) accs[i] = 0.0;
    }
    for (int idx = bid * 256 + t; idx < 128 * 200; idx += nb * 256) {
        const int row = idx / 200, c4 = idx % 200;
        ushort4 h = make_ushort4(0, 0, 0, 0), l = make_ushort4(0, 0, 0, 0);
        if (c4 < 196) {
            float4 v = reinterpret_cast<const float4*>(w + (size_t)row * 784)[c4];
            h.x = bf16_rne(v.x); h.y = bf16_rne(v.y); h.z = bf16_rne(v.z); h.w = bf16_rne(v.w);
            float4 hf = make_float4(__uint_as_float((unsigned)h.x << 16),
                                    __uint_as_float((unsigned)h.y << 16),
                                    __uint_as_float((unsigned)h.z << 16),
                                    __uint_as_float((unsigned)h.w << 16));
            l.x = bf16_rne(v.x - hf.x); l.y = bf16_rne(v.y - hf.y);
            l.z = bf16_rne(v.z - hf.z); l.w = bf16_rne(v.w - hf.w);
        }
        reinterpret_cast<ushort4*>(whi + (size_t)row * 800)[c4] = h;
        reinterpret_cast<ushort4*>(wlo + (size_t)row * 800)[c4] = l;
    }
    grid.sync();

    // ---- Phase A: o1 = selu(x @ w^T + b), split-bf16 MFMA, fused col stats
    {
        const int lr = lane & 15;
        const int lk = lane >> 4;
        for (int tile = gwid; tile < 4096; tile += totW) {
            const int rt = tile >> 3, ct = tile & 7;
            const float*  px  = x   + (size_t)(rt * 16 + lr) * 784 + lk * 8;
            const ushort* pbh = whi + (size_t)(ct * 16 + lr) * 800 + lk * 8;
            const ushort* pbl = wlo + (size_t)(ct * 16 + lr) * 800 + lk * 8;

            floatx4 acc = {};
#pragma unroll 2
            for (int k0 = 0; k0 < 768; k0 += 32) {
                bf16x8 ahi, alo;
                cvt8(px + k0, ahi, alo);
                bf16x8 bhi = *reinterpret_cast<const bf16x8*>(pbh + k0);
                bf16x8 blo = *reinterpret_cast<const bf16x8*>(pbl + k0);
                acc = __builtin_amdgcn_mfma_f32_16x16x32_bf16(alo, bhi, acc, 0, 0, 0);
                acc = __builtin_amdgcn_mfma_f32_16x16x32_bf16(ahi, blo, acc, 0, 0, 0);
                acc = __builtin_amdgcn_mfma_f32_16x16x32_bf16(ahi, bhi, acc, 0, 0, 0);
            }
            {   // peeled K tail (k0 = 768): k >= 784 -> zero fragments
                bf16x8 ahi = {}, alo = {};
                if (lk < 2) cvt8(px + 768, ahi, alo);
                bf16x8 bhi = *reinterpret_cast<const bf16x8*>(pbh + 768);
                bf16x8 blo = *reinterpret_cast<const bf16x8*>(pbl + 768);
                acc = __builtin_amdgcn_mfma_f32_16x16x32_bf16(alo, bhi, acc, 0, 0, 0);
                acc = __builtin_amdgcn_mfma_f32_16x16x32_bf16(ahi, blo, acc, 0, 0, 0);
                acc = __builtin_amdgcn_mfma_f32_16x16x32_bf16(ahi, bhi, acc, 0, 0, 0);
            }

            const int col = ct * 16 + lr;
            const float bias = fcb[col];
            float s = 0.f, s2 = 0.f;
#pragma unroll
            for (int j = 0; j < 4; ++j) {
                const int row = rt * 16 + lk * 4 + j;
                const float val = selu(acc[j] + bias);
                o1[(size_t)row * 128 + col] = val;
                s += val;
                s2 = fmaf(val, val, s2);
            }
            s  += __shfl_xor(s, 16);   s  += __shfl_xor(s, 32);
            s2 += __shfl_xor(s2, 16);  s2 += __shfl_xor(s2, 32);
            if (lane < 16) {
                atomicAdd(&sums[col],  (double)s);
                atomicAdd(&sumsq[col], (double)s2);
            }
        }
    }
    grid.sync();

    // ---- Phase C: BN normalize + fc2 + selu -> o_out, packed
    for (int row = gwid; row < 8192; row += totW) {
        float d0 = 0.f, d1 = 0.f;
#pragma unroll
        for (int half = 0; half < 2; ++half) {
            const int col = lane + half * 64;
            const float mu  = (float)(sums[col]  * (1.0 / 8192.0));
            const float ex2 = (float)(sumsq[col] * (1.0 / 8192.0));
            const float var = ex2 - mu * mu;
            const float inv = rsqrtf(var + 1e-5f);
            const float v = (o1[(size_t)row * 128 + col] - mu) * inv * gamma[col] + beta[col];
            d0 = fmaf(v, fc2w[col],       d0);
            d1 = fmaf(v, fc2w[128 + col], d1);
        }
#pragma unroll
        for (int off = 32; off >= 1; off >>= 1) {
            d0 += __shfl_down(d0, off);
            d1 += __shfl_down(d1, off);
        }
        if (lane == 0) {
            const float y0 = selu(d0 + fc2b[0]);
            const float y1 = selu(d1 + fc2b[1]);
            o_out[(size_t)row * 2 + 0] = y0;
            o_out[(size_t)row * 2 + 1] = y1;
            packed[row] = make_float4(y0, y1, y0 * y0 + y1 * y1, 0.f);
        }
    }
    grid.sync();

    // ---- Phase D: denom = 2 * sum_{i<j} 1/(1+dis) (accumulate, reduce once)
    {
        float accf = 0.f;
        for (int unit = bid; unit < 1024; unit += nb) {
            const int rb = (unit >> 3) * 64;
            const int cb = (unit & 7) * 1024;
            if (cb + 1024 <= rb) continue;          // all j < i
            const bool full = (cb >= rb + 64);      // all j > i

            float4 cd[4];
#pragma unroll
            for (int u = 0; u < 4; ++u) cd[u] = packed[cb + t + u * 256];

#pragma unroll 4
            for (int r = 0; r < 64; ++r) {
                const int i = rb + r;
                const float4 pi = packed[i];
#pragma unroll
                for (int u = 0; u < 4; ++u) {
                    float dis = pi.z + cd[u].z - 2.f * fmaf(pi.x, cd[u].x, pi.y * cd[u].y);
                    dis = fmaxf(dis, 0.f);
                    float f = fast_rcp(1.f + dis);
                    if (!full) {
                        const int j = cb + t + u * 256;
                        f = (j > i) ? f : 0.f;
                    }
                    accf += f;
                }
            }
        }
#pragma unroll
        for (int off = 32; off >= 1; off >>= 1) accf += __shfl_down(accf, off);
        if (lane == 0) wsum[wv] = (double)accf;
        __syncthreads();
        if (t == 0) {
            atomicAdd(denom, 2.0 * (wsum[0] + wsum[1] + wsum[2] + wsum[3]));
        }
    }
    grid.sync();

    // ---- Phase E: qij = (1/denom) / (1 + dis)
    {
        const float inv = (float)(1.0 / denom[0]);
        for (int unit = bid; unit < 1024; unit += nb) {
            const int rb = (unit >> 3) * 64;
            const int cb = (unit & 7) * 1024;

            float4 cd[4];
#pragma unroll
            for (int u = 0; u < 4; ++u) cd[u] = packed[cb + t * 4 + u];
            if (t < 64) rowsh[t] = packed[rb + t];
            __syncthreads();

#pragma unroll 2
            for (int r = 0; r < 64; ++r) {
                const float4 pi = rowsh[r];
                floatx4 q;
#pragma unroll
                for (int u = 0; u < 4; ++u) {
                    float dis = pi.z + cd[u].z - 2.f * fmaf(pi.x, cd[u].x, pi.y * cd[u].y);
                    dis = fmaxf(dis, 0.f);
                    q[u] = inv * fast_rcp(1.f + dis);
                }
                *reinterpret_cast<floatx4*>(&qij[(size_t)(rb + r) * 8192 + cb + t * 4]) = q;
            }
            __syncthreads();        // protect rowsh before next unit
        }
    }
}

// ===================== FALLBACK (non-cooperative) KERNELS ===================
__global__ __launch_bounds__(256) void convert_w_pad(
    const float* __restrict__ w, ushort* __restrict__ whi, ushort* __restrict__ wlo,
    double* __restrict__ accs)
{
    const int row = blockIdx.x;
    const int t   = threadIdx.x;
    if (row == 0 && t < 64) {
        for (int i = t; i < 257; i += 64) accs[i] = 0.0;
    }
    if (t < 196) {
        float4 v = reinterpret_cast<const float4*>(w + (size_t)row * 784)[t];
        ushort4 h, l;
        h.x = bf16_rne(v.x); h.y = bf16_rne(v.y); h.z = bf16_rne(v.z); h.w = bf16_rne(v.w);
        float4 hf = make_float4(__uint_as_float((unsigned)h.x << 16),
                                __uint_as_float((unsigned)h.y << 16),
                                __uint_as_float((unsigned)h.z << 16),
                                __uint_as_float((unsigned)h.w << 16));
        l.x = bf16_rne(v.x - hf.x); l.y = bf16_rne(v.y - hf.y);
        l.z = bf16_rne(v.z - hf.z); l.w = bf16_rne(v.w - hf.w);
        reinterpret_cast<ushort4*>(whi + (size_t)row * 800)[t] = h;
        reinterpret_cast<ushort4*>(wlo + (size_t)row * 800)[t] = l;
    } else if (t < 200) {
        const ushort4 z = make_ushort4(0, 0, 0, 0);
        reinterpret_cast<ushort4*>(whi + (size_t)row * 800)[t] = z;
        reinterpret_cast<ushort4*>(wlo + (size_t)row * 800)[t] = z;
    }
}

__global__ __launch_bounds__(256) void gemm1_mfma_stats(
    const float* __restrict__ x,
    const ushort* __restrict__ whi, const ushort* __restrict__ wlo,
    const float* __restrict__ b, float* __restrict__ o1,
    double* __restrict__ sums, double* __restrict__ sumsq)
{
    const int t    = threadIdx.x;
    const int lane = t & 63;
    const int wid  = blockIdx.x * 4 + (t >> 6);
    const int rt   = wid >> 3;
    const int ct   = wid & 7;
    const int lr   = lane & 15;
    const int lk   = lane >> 4;

    const float*  px  = x   + (size_t)(rt * 16 + lr) * 784 + lk * 8;
    const ushort* pbh = whi + (size_t)(ct * 16 + lr) * 800 + lk * 8;
    const ushort* pbl = wlo + (size_t)(ct * 16 + lr) * 800 + lk * 8;

    floatx4 acc = {};
#pragma unroll 2
    for (int k0 = 0; k0 < 768; k0 += 32) {
        bf16x8 ahi, alo;
        cvt8(px + k0, ahi, alo);
        bf16x8 bhi = *reinterpret_cast<const bf16x8*>(pbh + k0);
        bf16x8 blo = *reinterpret_cast<const bf16x8*>(pbl + k0);
        acc = __builtin_amdgcn_mfma_f32_16x16x32_bf16(alo, bhi, acc, 0, 0, 0);
        acc = __builtin_amdgcn_mfma_f32_16x16x32_bf16(ahi, blo, acc, 0, 0, 0);
        acc = __builtin_amdgcn_mfma_f32_16x16x32_bf16(ahi, bhi, acc, 0, 0, 0);
    }
    {
        bf16x8 ahi = {}, alo = {};
        if (lk < 2) cvt8(px + 768, ahi, alo);
        bf16x8 bhi = *reinterpret_cast<const bf16x8*>(pbh + 768);
        bf16x8 blo = *reinterpret_cast<const bf16x8*>(pbl + 768);
        acc = __builtin_amdgcn_mfma_f32_16x16x32_bf16(alo, bhi, acc, 0, 0, 0);
        acc = __builtin_amdgcn_mfma_f32_16x16x32_bf16(ahi, blo, acc, 0, 0, 0);
        acc = __builtin_amdgcn_mfma_f32_16x16x32_bf16(ahi, bhi, acc, 0, 0, 0);
    }

    const int col = ct * 16 + lr;
    const float bias = b[col];
    float s = 0.f, s2 = 0.f;
#pragma unroll
    for (int j = 0; j < 4; ++j) {
        const int row = rt * 16 + lk * 4 + j;
        const float val = selu(acc[j] + bias);
        o1[(size_t)row * 128 + col] = val;
        s += val;
        s2 = fmaf(val, val, s2);
    }
    s  += __shfl_xor(s, 16);   s  += __shfl_xor(s, 32);
    s2 += __shfl_xor(s2, 16);  s2 += __shfl_xor(s2, 32);
    if (lane < 16) {
        atomicAdd(&sums[col],  (double)s);
        atomicAdd(&sumsq[col], (double)s2);
    }
}

__global__ __launch_bounds__(256) void bn_fc2_selu(
    const float* __restrict__ o1, const double* __restrict__ sums, const double* __restrict__ sumsq,
    const float* __restrict__ gamma, const float* __restrict__ beta,
    const float* __restrict__ fc2w, const float* __restrict__ fc2b,
    float* __restrict__ o_out, float4* __restrict__ packed)
{
    const int wave = threadIdx.x >> 6;
    const int lane = threadIdx.x & 63;
    const int row  = blockIdx.x * 4 + wave;

    float d0 = 0.f, d1 = 0.f;
#pragma unroll
    for (int half = 0; half < 2; ++half) {
        const int col = lane + half * 64;
        const float mu  = (float)(sums[col]  * (1.0 / 8192.0));
        const float ex2 = (float)(sumsq[col] * (1.0 / 8192.0));
        const float var = ex2 - mu * mu;
        const float inv = rsqrtf(var + 1e-5f);
        const float v = (o1[(size_t)row * 128 + col] - mu) * inv * gamma[col] + beta[col];
        d0 = fmaf(v, fc2w[col],       d0);
        d1 = fmaf(v, fc2w[128 + col], d1);
    }
#pragma unroll
    for (int off = 32; off >= 1; off >>= 1) {
        d0 += __shfl_down(d0, off);
        d1 += __shfl_down(d1, off);
    }
    if (lane == 0) {
        const float y0 = selu(d0 + fc2b[0]);
        const float y1 = selu(d1 + fc2b[1]);
        o_out[(size_t)row * 2 + 0] = y0;
        o_out[(size_t)row * 2 + 1] = y1;
        packed[row] = make_float4(y0, y1, y0 * y0 + y1 * y1, 0.f);
    }
}

__global__ __launch_bounds__(256) void denom_reduce(
    const float4* __restrict__ packed, double* __restrict__ denom)
{
    const int rb = blockIdx.x * 64;
    const int cb = blockIdx.y * 1024;
    if (cb + 1024 <= rb) return;
    const int t = threadIdx.x;
    const bool full = (cb >= rb + 64);

    float4 cd[4];
#pragma unroll
    for (int u = 0; u < 4; ++u) cd[u] = packed[cb + t + u * 256];

    float accf = 0.f;
#pragma unroll 4
    for (int r = 0; r < 64; ++r) {
        const int i = rb + r;
        const float4 pi = packed[i];
#pragma unroll
        for (int u = 0; u < 4; ++u) {
            float dis = pi.z + cd[u].z - 2.f * fmaf(pi.x, cd[u].x, pi.y * cd[u].y);
            dis = fmaxf(dis, 0.f);
            float f = fast_rcp(1.f + dis);
            if (!full) {
                const int j = cb + t + u * 256;
                f = (j > i) ? f : 0.f;
            }
            accf += f;
        }
    }
#pragma unroll
    for (int off = 32; off >= 1; off >>= 1) accf += __shfl_down(accf, off);
    __shared__ double wsum[4];
    const int wave = t >> 6, lane = t & 63;
    if (lane == 0) wsum[wave] = (double)accf;
    __syncthreads();
    if (t == 0) atomicAdd(denom, 2.0 * (wsum[0] + wsum[1] + wsum[2] + wsum[3]));
}

__global__ __launch_bounds__(256) void qij_write(
    const float4* __restrict__ packed, const double* __restrict__ denom,
    float* __restrict__ qij)
{
    __shared__ float4 rowsh[64];
    const int t  = threadIdx.x;
    const int cb = blockIdx.y * 1024;
    const int rb = blockIdx.x * 64;

    float4 cd[4];
#pragma unroll
    for (int u = 0; u < 4; ++u) cd[u] = packed[cb + t * 4 + u];
    if (t < 64) rowsh[t] = packed[rb + t];

    const float inv = (float)(1.0 / denom[0]);
    __syncthreads();

#pragma unroll 2
    for (int r = 0; r < 64; ++r) {
        const float4 pi = rowsh[r];
        floatx4 q;
#pragma unroll
        for (int u = 0; u < 4; ++u) {
            float dis = pi.z + cd[u].z - 2.f * fmaf(pi.x, cd[u].x, pi.y * cd[u].y);
            dis = fmaxf(dis, 0.f);
            q[u] = inv * fast_rcp(1.f + dis);
        }
        *reinterpret_cast<floatx4*>(&qij[(size_t)(rb + r) * 8192 + cb + t * 4]) = q;
    }
}

// ---------------------------------------------------------------------------
extern "C" void kernel_launch(void* const* d_in, const int* in_sizes, int n_in,
                              void* d_out, int out_size, void* d_ws, size_t ws_size,
                              hipStream_t stream)
{
    const float* x      = (const float*)d_in[0];
    const float* fc_w   = (const float*)d_in[1];
    const float* fc_b   = (const float*)d_in[2];
    const float* gamma  = (const float*)d_in[3];
    const float* beta   = (const float*)d_in[4];
    const float* fc2_w  = (const float*)d_in[5];
    const float* fc2_b  = (const float*)d_in[6];

    constexpr int N = 8192;

    float* qij   = (float*)d_out;                          // [N, N]
    float* o_out = (float*)d_out + (size_t)N * N;          // [N, 2]

    char* ws = (char*)d_ws;
    constexpr size_t O1_OFF     = 0;                          // 4 MB
    constexpr size_t ACC_OFF    = (size_t)N * 128 * 4;        // 257 doubles
    constexpr size_t PACKED_OFF = ACC_OFF + 4096;             // 128 KB
    constexpr size_t WHI_OFF    = PACKED_OFF + (size_t)N * 16;
    constexpr size_t WPLANE     = ((size_t)128 * 800 * 2 + 63) / 64 * 64;
    constexpr size_t WLO_OFF    = WHI_OFF + WPLANE;

    float*  o1     = (float*)(ws + O1_OFF);
    double* accs   = (double*)(ws + ACC_OFF);
    double* sums   = accs;
    double* sumsq  = accs + 128;
    double* denom  = accs + 256;
    float4* packed = (float4*)(ws + PACKED_OFF);
    ushort* whi    = (ushort*)(ws + WHI_OFF);
    ushort* wlo    = (ushort*)(ws + WLO_OFF);

    // size the cooperative grid by occupancy (deterministic per build)
    int blocksPerCU = 0;
    hipError_t qerr = hipOccupancyMaxActiveBlocksPerMultiprocessor(
        &blocksPerCU, fused_all, 256, 0);
    int nblocks = 1024;
    if (qerr == hipSuccess && blocksPerCU > 0) {
        int cap = blocksPerCU * 256;
        if (cap < nblocks) nblocks = cap;
    }

    void* args[] = {
        (void*)&x, (void*)&fc_w, (void*)&fc_b, (void*)&gamma, (void*)&beta,
        (void*)&fc2_w, (void*)&fc2_b, (void*)&o1, (void*)&accs, (void*)&packed,
        (void*)&whi, (void*)&wlo, (void*)&o_out, (void*)&qij
    };
    hipError_t lerr = hipLaunchCooperativeKernel(
        fused_all, dim3(nblocks), dim3(256), args, 0, stream);

    if (lerr != hipSuccess) {
        // Fallback: non-cooperative 5-kernel pipeline (same math)
        convert_w_pad<<<128, 256, 0, stream>>>(fc_w, whi, wlo, accs);
        gemm1_mfma_stats<<<1024, 256, 0, stream>>>(x, whi, wlo, fc_b, o1, sums, sumsq);
        bn_fc2_selu<<<N / 4, 256, 0, stream>>>(o1, sums, sumsq, gamma, beta,
                                               fc2_w, fc2_b, o_out, packed);
        denom_reduce<<<dim3(N / 64, N / 1024), 256, 0, stream>>>(packed, denom);
        qij_write<<<dim3(N / 64, N / 1024), 256, 0, stream>>>(packed, denom, qij);
    }
}

// Round 12
// 113.743 us; speedup vs baseline: 2.6942x; 2.6942x over previous
//
#include <hip/hip_runtime.h>
#include <hip/hip_bf16.h>

#define SELU_L 1.0507009873554805f
#define SELU_A 1.6732632423543772f

typedef float  floatx4 __attribute__((ext_vector_type(4)));
typedef short  bf16x8  __attribute__((ext_vector_type(8)));

__device__ __forceinline__ float selu(float x) {
    return x > 0.f ? SELU_L * x : SELU_L * SELU_A * (expf(x) - 1.f);
}
__device__ __forceinline__ float fast_rcp(float x) {
    return __builtin_amdgcn_rcpf(x);
}
__device__ __forceinline__ unsigned short bf16_rne(float f) {
    unsigned int u = __float_as_uint(f);
    u += 0x7fffu + ((u >> 16) & 1u);
    return (unsigned short)(u >> 16);
}
__device__ __forceinline__ void cvt8(const float* __restrict__ p,
                                     bf16x8& h8, bf16x8& l8) {
    float4 v0 = *reinterpret_cast<const float4*>(p);
    float4 v1 = *reinterpret_cast<const float4*>(p + 4);
    float f[8] = {v0.x, v0.y, v0.z, v0.w, v1.x, v1.y, v1.z, v1.w};
#pragma unroll
    for (int j = 0; j < 8; ++j) {
        const unsigned short h = bf16_rne(f[j]);
        const float hf = __uint_as_float((unsigned)h << 16);
        const unsigned short l = bf16_rne(f[j] - hf);
        h8[j] = (short)h;
        l8[j] = (short)l;
    }
}

// ---------------- Kernel W: convert fc_w into bf16 hi/lo planes -------------
__global__ __launch_bounds__(256) void convert_w_pad(
    const float* __restrict__ w, ushort* __restrict__ whi, ushort* __restrict__ wlo,
    double* __restrict__ accs)
{
    const int row = blockIdx.x;           // 0..127
    const int t   = threadIdx.x;
    if (row == 0 && t < 64) {
        for (int i = t; i < 257; i += 64) accs[i] = 0.0;
    }
    if (t < 196) {
        float4 v = reinterpret_cast<const float4*>(w + (size_t)row * 784)[t];
        ushort4 h, l;
        h.x = bf16_rne(v.x); h.y = bf16_rne(v.y); h.z = bf16_rne(v.z); h.w = bf16_rne(v.w);
        float4 hf = make_float4(__uint_as_float((unsigned)h.x << 16),
                                __uint_as_float((unsigned)h.y << 16),
                                __uint_as_float((unsigned)h.z << 16),
                                __uint_as_float((unsigned)h.w << 16));
        l.x = bf16_rne(v.x - hf.x); l.y = bf16_rne(v.y - hf.y);
        l.z = bf16_rne(v.z - hf.z); l.w = bf16_rne(v.w - hf.w);
        reinterpret_cast<ushort4*>(whi + (size_t)row * 800)[t] = h;
        reinterpret_cast<ushort4*>(wlo + (size_t)row * 800)[t] = l;
    } else if (t < 200) {
        const ushort4 z = make_ushort4(0, 0, 0, 0);
        reinterpret_cast<ushort4*>(whi + (size_t)row * 800)[t] = z;
        reinterpret_cast<ushort4*>(wlo + (size_t)row * 800)[t] = z;
    }
}

// ---------------- Kernel A: o1 = selu(x @ w^T + b), split-bf16 MFMA ---------
__global__ __launch_bounds__(256) void gemm1_mfma_stats(
    const float* __restrict__ x,
    const ushort* __restrict__ whi, const ushort* __restrict__ wlo,
    const float* __restrict__ b, float* __restrict__ o1,
    double* __restrict__ sums, double* __restrict__ sumsq)
{
    const int t    = threadIdx.x;
    const int lane = t & 63;
    const int wid  = blockIdx.x * 4 + (t >> 6);
    const int rt   = wid >> 3;
    const int ct   = wid & 7;
    const int lr   = lane & 15;
    const int lk   = lane >> 4;

    const float*  px  = x   + (size_t)(rt * 16 + lr) * 784 + lk * 8;
    const ushort* pbh = whi + (size_t)(ct * 16 + lr) * 800 + lk * 8;
    const ushort* pbl = wlo + (size_t)(ct * 16 + lr) * 800 + lk * 8;

    floatx4 acc = {};
#pragma unroll 2
    for (int k0 = 0; k0 < 768; k0 += 32) {
        bf16x8 ahi, alo;
        cvt8(px + k0, ahi, alo);
        bf16x8 bhi = *reinterpret_cast<const bf16x8*>(pbh + k0);
        bf16x8 blo = *reinterpret_cast<const bf16x8*>(pbl + k0);
        acc = __builtin_amdgcn_mfma_f32_16x16x32_bf16(alo, bhi, acc, 0, 0, 0);
        acc = __builtin_amdgcn_mfma_f32_16x16x32_bf16(ahi, blo, acc, 0, 0, 0);
        acc = __builtin_amdgcn_mfma_f32_16x16x32_bf16(ahi, bhi, acc, 0, 0, 0);
    }
    {   // peeled K tail (k0 = 768): k >= 784 -> zero fragments
        bf16x8 ahi = {}, alo = {};
        if (lk < 2) cvt8(px + 768, ahi, alo);
        bf16x8 bhi = *reinterpret_cast<const bf16x8*>(pbh + 768);
        bf16x8 blo = *reinterpret_cast<const bf16x8*>(pbl + 768);
        acc = __builtin_amdgcn_mfma_f32_16x16x32_bf16(alo, bhi, acc, 0, 0, 0);
        acc = __builtin_amdgcn_mfma_f32_16x16x32_bf16(ahi, blo, acc, 0, 0, 0);
        acc = __builtin_amdgcn_mfma_f32_16x16x32_bf16(ahi, bhi, acc, 0, 0, 0);
    }

    const int col = ct * 16 + lr;
    const float bias = b[col];
    float s = 0.f, s2 = 0.f;
#pragma unroll
    for (int j = 0; j < 4; ++j) {
        const int row = rt * 16 + lk * 4 + j;
        const float val = selu(acc[j] + bias);
        o1[(size_t)row * 128 + col] = val;
        s += val;
        s2 = fmaf(val, val, s2);
    }
    s  += __shfl_xor(s, 16);   s  += __shfl_xor(s, 32);
    s2 += __shfl_xor(s2, 16);  s2 += __shfl_xor(s2, 32);
    if (lane < 16) {
        atomicAdd(&sums[col],  (double)s);
        atomicAdd(&sumsq[col], (double)s2);
    }
}

// ---------------- Kernel C: BN normalize + fc2 + selu -----------------------
__global__ __launch_bounds__(256) void bn_fc2_selu(
    const float* __restrict__ o1, const double* __restrict__ sums, const double* __restrict__ sumsq,
    const float* __restrict__ gamma, const float* __restrict__ beta,
    const float* __restrict__ fc2w, const float* __restrict__ fc2b,
    float* __restrict__ o_out, float4* __restrict__ packed)
{
    const int wave = threadIdx.x >> 6;
    const int lane = threadIdx.x & 63;
    const int row  = blockIdx.x * 4 + wave;

    float d0 = 0.f, d1 = 0.f;
#pragma unroll
    for (int half = 0; half < 2; ++half) {
        const int col = lane + half * 64;
        const float mu  = (float)(sums[col]  * (1.0 / 8192.0));
        const float ex2 = (float)(sumsq[col] * (1.0 / 8192.0));
        const float var = ex2 - mu * mu;
        const float inv = rsqrtf(var + 1e-5f);
        const float v = (o1[(size_t)row * 128 + col] - mu) * inv * gamma[col] + beta[col];
        d0 = fmaf(v, fc2w[col],       d0);
        d1 = fmaf(v, fc2w[128 + col], d1);
    }
#pragma unroll
    for (int off = 32; off >= 1; off >>= 1) {
        d0 += __shfl_down(d0, off);
        d1 += __shfl_down(d1, off);
    }
    if (lane == 0) {
        const float y0 = selu(d0 + fc2b[0]);
        const float y1 = selu(d1 + fc2b[1]);
        o_out[(size_t)row * 2 + 0] = y0;
        o_out[(size_t)row * 2 + 1] = y1;
        packed[row] = make_float4(y0, y1, y0 * y0 + y1 * y1, 0.f);
    }
}

// ---------------- Kernel D: denom = 2 * sum_{i<j} 1/(1+dis) -----------------
__global__ __launch_bounds__(256) void denom_reduce(
    const float4* __restrict__ packed, double* __restrict__ denom)
{
    const int rb = blockIdx.x * 64;
    const int cb = blockIdx.y * 1024;
    if (cb + 1024 <= rb) return;
    const int t = threadIdx.x;
    const bool full = (cb >= rb + 64);

    float4 cd[4];
#pragma unroll
    for (int u = 0; u < 4; ++u) cd[u] = packed[cb + t + u * 256];

    float accf = 0.f;
#pragma unroll 4
    for (int r = 0; r < 64; ++r) {
        const int i = rb + r;
        const float4 pi = packed[i];
#pragma unroll
        for (int u = 0; u < 4; ++u) {
            float dis = pi.z + cd[u].z - 2.f * fmaf(pi.x, cd[u].x, pi.y * cd[u].y);
            dis = fmaxf(dis, 0.f);
            float f = fast_rcp(1.f + dis);
            if (!full) {
                const int j = cb + t + u * 256;
                f = (j > i) ? f : 0.f;
            }
            accf += f;
        }
    }
#pragma unroll
    for (int off = 32; off >= 1; off >>= 1) accf += __shfl_down(accf, off);
    __shared__ double wsum[4];
    const int wave = t >> 6, lane = t & 63;
    if (lane == 0) wsum[wave] = (double)accf;
    __syncthreads();
    if (t == 0) atomicAdd(denom, 2.0 * (wsum[0] + wsum[1] + wsum[2] + wsum[3]));
}

// ---------------- Kernel E: qij write, CONTIGUOUS-SLAB layout ---------------
// 512 blocks x 512 threads. Block b owns rows b*16..b*16+15 = a contiguous
// 512 KB slab of qij (mimics the fill's streaming pattern). Each thread owns
// 16 fixed columns held in registers (cd[4][4], static indexing).
__global__ __launch_bounds__(512) void qij_write_slab(
    const float4* __restrict__ packed, const double* __restrict__ denom,
    float* __restrict__ qij)
{
    const int t  = threadIdx.x;              // 0..511
    const int rb = blockIdx.x * 16;
    const float inv = (float)(1.0 / denom[0]);

    // hoisted column data: cols c*2048 + t*4 + u  (64 VGPRs, loop-invariant)
    float4 cd[4][4];
#pragma unroll
    for (int c = 0; c < 4; ++c)
#pragma unroll
        for (int u = 0; u < 4; ++u)
            cd[c][u] = packed[c * 2048 + t * 4 + u];

#pragma unroll 2
    for (int r = 0; r < 16; ++r) {
        const int j = rb + r;
        const float4 pi = packed[j];         // uniform -> scalar load (L2)
        float* outrow = qij + (size_t)j * 8192 + t * 4;
#pragma unroll
        for (int c = 0; c < 4; ++c) {
            floatx4 q;
#pragma unroll
            for (int u = 0; u < 4; ++u) {
                float dis = pi.z + cd[c][u].z
                          - 2.f * fmaf(pi.x, cd[c][u].x, pi.y * cd[c][u].y);
                dis = fmaxf(dis, 0.f);
                q[u] = inv * fast_rcp(1.f + dis);
            }
            *reinterpret_cast<floatx4*>(outrow + c * 2048) = q;
        }
    }
}

// ---------------------------------------------------------------------------
extern "C" void kernel_launch(void* const* d_in, const int* in_sizes, int n_in,
                              void* d_out, int out_size, void* d_ws, size_t ws_size,
                              hipStream_t stream)
{
    const float* x      = (const float*)d_in[0];
    const float* fc_w   = (const float*)d_in[1];
    const float* fc_b   = (const float*)d_in[2];
    const float* gamma  = (const float*)d_in[3];
    const float* beta   = (const float*)d_in[4];
    const float* fc2_w  = (const float*)d_in[5];
    const float* fc2_b  = (const float*)d_in[6];

    constexpr int N = 8192;

    float* qij   = (float*)d_out;                          // [N, N]
    float* o_out = (float*)d_out + (size_t)N * N;          // [N, 2]

    char* ws = (char*)d_ws;
    constexpr size_t O1_OFF     = 0;                          // 4 MB
    constexpr size_t ACC_OFF    = (size_t)N * 128 * 4;        // 257 doubles
    constexpr size_t PACKED_OFF = ACC_OFF + 4096;             // 128 KB
    constexpr size_t WHI_OFF    = PACKED_OFF + (size_t)N * 16;
    constexpr size_t WPLANE     = ((size_t)128 * 800 * 2 + 63) / 64 * 64;
    constexpr size_t WLO_OFF    = WHI_OFF + WPLANE;

    float*  o1     = (float*)(ws + O1_OFF);
    double* accs   = (double*)(ws + ACC_OFF);              // sums|sumsq|denom
    double* sums   = accs;
    double* sumsq  = accs + 128;
    double* denom  = accs + 256;
    float4* packed = (float4*)(ws + PACKED_OFF);
    ushort* whi    = (ushort*)(ws + WHI_OFF);
    ushort* wlo    = (ushort*)(ws + WLO_OFF);

    // W: convert fc_w to bf16 hi/lo planes (K padded to 800), zero accs
    convert_w_pad<<<128, 256, 0, stream>>>(fc_w, whi, wlo, accs);

    // A: o1 = selu(x @ fc_w^T + fc_b), inline x split, fused column stats
    gemm1_mfma_stats<<<1024, 256, 0, stream>>>(x, whi, wlo, fc_b, o1, sums, sumsq);

    // C: normalize + fc2 + selu -> o_out, packed
    bn_fc2_selu<<<N / 4, 256, 0, stream>>>(o1, sums, sumsq, gamma, beta, fc2_w, fc2_b, o_out, packed);

    // D: denom = 2 * sum_{i<j} 1/(1+dis)
    denom_reduce<<<dim3(N / 64, N / 1024), 256, 0, stream>>>(packed, denom);

    // E: qij = (1/denom) / (1 + dis), contiguous 512 KB slab per block
    qij_write_slab<<<512, 512, 0, stream>>>(packed, denom, qij);
}